// Round 2
// baseline (644.049 us; speedup 1.0000x reference)
//
#include <hip/hip_runtime.h>
#include <math.h>

#define BT_TOTAL 65536
#define DIN 512
#define DEMB 256
#define KCODES 1024

typedef __attribute__((ext_vector_type(8))) short short8;
typedef __attribute__((ext_vector_type(4))) float floatx4;
typedef __attribute__((ext_vector_type(16))) float floatx16;

__device__ __forceinline__ unsigned short f2bf(float x) {
    unsigned u = __float_as_uint(x);
    unsigned r = u + 0x7fffu + ((u >> 16) & 1u);
    return (unsigned short)(r >> 16);
}
__device__ __forceinline__ float bf2f(unsigned short h) {
    return __uint_as_float(((unsigned)h) << 16);
}

// ---------------- K0a: codebook row norms + zero loss outputs ---------------
__global__ __launch_bounds__(256) void cnorm_kernel(const float* __restrict__ cbook,
                                                    float* __restrict__ cnorm,
                                                    float* __restrict__ out_loss) {
    const int k = blockIdx.x;
    const int tid = threadIdx.x;
    float v = cbook[k * DEMB + tid];
    v *= v;
#pragma unroll
    for (int o = 32; o > 0; o >>= 1) v += __shfl_down(v, o);
    __shared__ float ps[4];
    if ((tid & 63) == 0) ps[tid >> 6] = v;
    __syncthreads();
    if (tid == 0) cnorm[k] = ps[0] + ps[1] + ps[2] + ps[3];
    if (k == 0 && tid < 32) out_loss[tid] = 0.0f;
}

// ---------------- K0b: split+swizzle [N][K] row-major into 16x16x32 MFMA
// B-frag order (used by gemm_down): offset(c,k) = (((c>>4)*(K/32)+(k>>5))*64+lane)*8+(k&7),
// lane = ((k>>3)&3)*16 + (c&15).
__global__ __launch_bounds__(256) void swz_kernel(const float* __restrict__ Bt,
                                                  unsigned short* __restrict__ hi,
                                                  unsigned short* __restrict__ lo,
                                                  int K, int total) {
    const int o = blockIdx.x * 256 + threadIdx.x;
    if (o >= total) return;
    const int j = o & 7;
    const int l = (o >> 3) & 63;
    const int r = o >> 9;
    const int kst = K >> 5;
    const int s = r % kst;
    const int t = r / kst;
    const int c = t * 16 + (l & 15);
    const int k = s * 32 + (l >> 4) * 8 + j;
    const float v = Bt[(size_t)c * K + k];
    const unsigned short h = f2bf(v);
    hi[o] = (unsigned short)h;
    lo[o] = f2bf(v - bf2f(h));
}

// ---------------- K0c: split+swizzle [N][K] row-major into 32x32x16 MFMA
// B-frag order (used by dist): for code c, depth k:
//   t = c>>5 (32-code tile), s = k>>4 (16-deep chunk),
//   lane = ((k>>3)&1)*32 + (c&31), j = k&7
//   offset = ((t*(K/16) + s)*64 + lane)*8 + j
__global__ __launch_bounds__(256) void swz32_kernel(const float* __restrict__ Bt,
                                                    unsigned short* __restrict__ hi,
                                                    unsigned short* __restrict__ lo,
                                                    int K, int total) {
    const int o = blockIdx.x * 256 + threadIdx.x;
    if (o >= total) return;
    const int j = o & 7;
    const int l = (o >> 3) & 63;
    const int r = o >> 9;
    const int kst = K >> 4;
    const int s = r % kst;
    const int t = r / kst;
    const int c = t * 32 + (l & 31);
    const int k = s * 16 + (l >> 5) * 8 + j;
    const float v = Bt[(size_t)c * K + k];
    const unsigned short h = f2bf(v);
    hi[o] = (unsigned short)h;
    lo[o] = f2bf(v - bf2f(h));
}

// ---------------- fp32 VALU GEMM (for tiny P-matrix): C = A * Bt^T ----------
template <int KD, int NSTR>
__global__ __launch_bounds__(256) void gemm_rowdot(const float* __restrict__ A,
                                                   const float* __restrict__ Bt,
                                                   float* __restrict__ C) {
    __shared__ __align__(16) float As[64][36];
    __shared__ __align__(16) float Bs[64][36];
    const int tid = threadIdx.x;
    const int tx = tid & 15, ty = tid >> 4;
    const int rowBase = blockIdx.x * 64;
    const int colBase = blockIdx.y * 64;
    const int lr = tid >> 2;
    const int lk = (tid & 3) * 8;
    float acc[4][4] = {};
    for (int k0 = 0; k0 < KD; k0 += 32) {
        const float4 a0 = *(const float4*)(A + (size_t)(rowBase + lr) * KD + k0 + lk);
        const float4 a1 = *(const float4*)(A + (size_t)(rowBase + lr) * KD + k0 + lk + 4);
        const float4 b0 = *(const float4*)(Bt + (size_t)(colBase + lr) * KD + k0 + lk);
        const float4 b1 = *(const float4*)(Bt + (size_t)(colBase + lr) * KD + k0 + lk + 4);
        __syncthreads();
        *(float4*)&As[lr][lk] = a0;
        *(float4*)&As[lr][lk + 4] = a1;
        *(float4*)&Bs[lr][lk] = b0;
        *(float4*)&Bs[lr][lk + 4] = b1;
        __syncthreads();
#pragma unroll
        for (int e = 0; e < 32; e += 4) {
            float4 va[4], vb[4];
#pragma unroll
            for (int i = 0; i < 4; ++i) va[i] = *(const float4*)&As[4 * ty + i][e];
#pragma unroll
            for (int j = 0; j < 4; ++j) vb[j] = *(const float4*)&Bs[4 * tx + j][e];
#pragma unroll
            for (int i = 0; i < 4; ++i)
#pragma unroll
                for (int j = 0; j < 4; ++j) {
                    acc[i][j] = fmaf(va[i].x, vb[j].x, acc[i][j]);
                    acc[i][j] = fmaf(va[i].y, vb[j].y, acc[i][j]);
                    acc[i][j] = fmaf(va[i].z, vb[j].z, acc[i][j]);
                    acc[i][j] = fmaf(va[i].w, vb[j].w, acc[i][j]);
                }
        }
    }
#pragma unroll
    for (int i = 0; i < 4; ++i) {
        float4 o = make_float4(acc[i][0], acc[i][1], acc[i][2], acc[i][3]);
        *(float4*)(C + (size_t)(rowBase + 4 * ty + i) * NSTR + colBase + 4 * tx) = o;
    }
}

// ---------------- K1: z_e_down = z_e @ W_down^T  (MFMA bf16x2, LDS-staged B)
__global__ __launch_bounds__(256) void gemm_down_mfma(const float* __restrict__ A,
                                                      const unsigned short* __restrict__ bhi,
                                                      const unsigned short* __restrict__ blo,
                                                      float* __restrict__ C) {
    __shared__ __align__(16) short lds_h[16][512];  // [t][lane*8] for current s
    __shared__ __align__(16) short lds_l[16][512];
    const int tid = threadIdx.x;
    const int lane = tid & 63, wv = tid >> 6;
    const int m = lane & 15, q = lane >> 4;
    const int rowBase = blockIdx.x * 64 + wv * 16;

    floatx4 acc[16];
#pragma unroll
    for (int t = 0; t < 16; ++t) acc[t] = (floatx4){0.f, 0.f, 0.f, 0.f};

    for (int s = 0; s < 16; ++s) {  // K = 512, chunks of 32
        // A chunk for this wave's rows (global, overlaps barrier wait)
        const float4* ap = (const float4*)(A + (size_t)(rowBase + m) * DIN + s * 32 + q * 8);
        const float4 v0 = ap[0], v1 = ap[1];
        __syncthreads();  // previous-iteration LDS reads done
        // stage B fragments for this s: 32 chunks of 1 KB over 4 waves
#pragma unroll
        for (int i = 0; i < 8; ++i) {
            const int c = wv * 8 + i;
            const int t = c >> 1;
            const unsigned short* src = (c & 1) ? blo : bhi;
            const short8 vst = *(const short8*)(src + ((size_t)(t * 16 + s) * 64 + lane) * 8);
            short* dst = (c & 1) ? &lds_l[t][lane * 8] : &lds_h[t][lane * 8];
            *(short8*)dst = vst;
        }
        // convert A to hi/lo fragments
        const float xs[8] = {v0.x, v0.y, v0.z, v0.w, v1.x, v1.y, v1.z, v1.w};
        short8 ahi, alo;
#pragma unroll
        for (int j = 0; j < 8; ++j) {
            const unsigned short h = f2bf(xs[j]);
            ahi[j] = (short)h;
            alo[j] = (short)f2bf(xs[j] - bf2f(h));
        }
        __syncthreads();
#pragma unroll
        for (int t = 0; t < 16; ++t) {
            const short8 bh = *(const short8*)&lds_h[t][lane * 8];
            const short8 bl = *(const short8*)&lds_l[t][lane * 8];
            acc[t] = __builtin_amdgcn_mfma_f32_16x16x32_bf16(ahi, bh, acc[t], 0, 0, 0);
            acc[t] = __builtin_amdgcn_mfma_f32_16x16x32_bf16(alo, bh, acc[t], 0, 0, 0);
            acc[t] = __builtin_amdgcn_mfma_f32_16x16x32_bf16(ahi, bl, acc[t], 0, 0, 0);
        }
    }
#pragma unroll
    for (int t = 0; t < 16; ++t)
#pragma unroll
        for (int r = 0; r < 4; ++r)
            C[(size_t)(rowBase + q * 4 + r) * DEMB + t * 16 + m] = acc[t][r];
}

// ---------------- K2: dist + argmin + losses -------------------------------
// v3: barrier-free main loop. Block = 32 rows; A hi/lo fragments staged ONCE
// into shared LDS (32 KB, one barrier); 4 waves split the 1024 codes 4-way
// (8 tiles of 32 each); B streamed from global (L2-resident, 1 MB) via a
// depth-4 register prefetch. Grid = 2048 -> up to 12 waves/CU, all
// independent. Epilogue: cross-wave argmin merge via 1 KB LDS table.
__global__ __launch_bounds__(256, 3) void dist_mfma(const float* __restrict__ zed,
                                                    const unsigned short* __restrict__ chi,
                                                    const unsigned short* __restrict__ clo,
                                                    const float* __restrict__ cnorm,
                                                    float* __restrict__ out_code,
                                                    float* __restrict__ out_loss) {
    __shared__ __align__(16) short lds_ah[16][512];  // [chunk][lane*8]
    __shared__ __align__(16) short lds_al[16][512];
    __shared__ float znp[4][64];      // per-wave znorm partials (row=lane&31, half)
    __shared__ float cand_v[4][32];   // per-wave best value per row
    __shared__ int cand_i[4][32];     // per-wave best code per row
    const int tid = threadIdx.x;
    const int lane = tid & 63, wv = tid >> 6;
    const int cc = lane & 31, half = lane >> 5;
    const int rowBase = blockIdx.x * 32;

    // ---- stage A: wave wv converts chunks 4wv..4wv+3 for all 32 rows ----
    {
        float zn = 0.f;
        const float* arow = zed + (size_t)(rowBase + cc) * DEMB + half * 8;
#pragma unroll
        for (int i = 0; i < 4; ++i) {
            const int s = wv * 4 + i;
            const float4 v0 = *(const float4*)(arow + s * 16);
            const float4 v1 = *(const float4*)(arow + s * 16 + 4);
            const float xs[8] = {v0.x, v0.y, v0.z, v0.w, v1.x, v1.y, v1.z, v1.w};
            short8 h8, l8;
#pragma unroll
            for (int j = 0; j < 8; ++j) {
                const unsigned short h = f2bf(xs[j]);
                h8[j] = (short)h;
                l8[j] = (short)f2bf(xs[j] - bf2f(h));
                zn = fmaf(xs[j], xs[j], zn);
            }
            *(short8*)&lds_ah[s][lane * 8] = h8;
            *(short8*)&lds_al[s][lane * 8] = l8;
        }
        znp[wv][lane] = zn;
    }
    __syncthreads();  // the ONLY pre-epilogue barrier

    // ---- main loop: wave wv handles tiles wv*8 .. wv*8+7 (codes wv*256..) --
    floatx16 accA, accB;
    float bestv[16];
    int besti[16];
#pragma unroll
    for (int r = 0; r < 16; ++r) {
        accA[r] = 0.f;
        accB[r] = 0.f;
        bestv[r] = INFINITY;
        besti[r] = 0;
    }

    const unsigned short* bhp = chi + (size_t)(wv * 8) * 8192 + lane * 8;
    const unsigned short* blp = clo + (size_t)(wv * 8) * 8192 + lane * 8;
    short8 pfh[4], pfl[4];
#pragma unroll
    for (int i = 0; i < 4; ++i) {
        pfh[i] = *(const short8*)(bhp + i * 512);
        pfl[i] = *(const short8*)(blp + i * 512);
    }

    for (int tt = 0; tt < 8; ++tt) {
        const int code = (wv * 8 + tt) * 32 + cc;
        const float cn = cnorm[code];  // L2-hit scalar-ish load, prefetched early
        const unsigned short* bhn = bhp + ((tt < 7) ? 8192 : 0);
        const unsigned short* bln = blp + ((tt < 7) ? 8192 : 0);
#pragma unroll
        for (int s = 0; s < 16; ++s) {
            const short8 vh = pfh[s & 3];
            const short8 vl = pfl[s & 3];
            if (s < 12) {  // prefetch chunk s+4 of this tile
                pfh[s & 3] = *(const short8*)(bhp + (s + 4) * 512);
                pfl[s & 3] = *(const short8*)(blp + (s + 4) * 512);
            } else {  // prefetch chunk s-12 of next tile
                pfh[s & 3] = *(const short8*)(bhn + (s - 12) * 512);
                pfl[s & 3] = *(const short8*)(bln + (s - 12) * 512);
            }
            const short8 ah = *(const short8*)&lds_ah[s][lane * 8];
            const short8 al = *(const short8*)&lds_al[s][lane * 8];
            if (s & 1) {
                accB = __builtin_amdgcn_mfma_f32_32x32x16_bf16(ah, vh, accB, 0, 0, 0);
                accB = __builtin_amdgcn_mfma_f32_32x32x16_bf16(al, vh, accB, 0, 0, 0);
                accB = __builtin_amdgcn_mfma_f32_32x32x16_bf16(ah, vl, accB, 0, 0, 0);
            } else {
                accA = __builtin_amdgcn_mfma_f32_32x32x16_bf16(ah, vh, accA, 0, 0, 0);
                accA = __builtin_amdgcn_mfma_f32_32x32x16_bf16(al, vh, accA, 0, 0, 0);
                accA = __builtin_amdgcn_mfma_f32_32x32x16_bf16(ah, vl, accA, 0, 0, 0);
            }
        }
#pragma unroll
        for (int r = 0; r < 16; ++r) {
            const float d = fmaf(-2.f, accA[r] + accB[r], cn);
            if (d < bestv[r]) {
                bestv[r] = d;
                besti[r] = code;
            }
            accA[r] = 0.f;
            accB[r] = 0.f;
        }
        bhp = bhn;
        blp = bln;
    }

    // per-wave reduce across the 32 code-lanes (first-index tie-break)
#pragma unroll
    for (int off = 1; off < 32; off <<= 1) {
#pragma unroll
        for (int r = 0; r < 16; ++r) {
            const float ov = __shfl_xor(bestv[r], off, 64);
            const int oi = __shfl_xor(besti[r], off, 64);
            if (ov < bestv[r] || (ov == bestv[r] && oi < besti[r])) {
                bestv[r] = ov;
                besti[r] = oi;
            }
        }
    }
    if (cc == 0) {  // lanes 0 and 32 hold the 32 rows between them
#pragma unroll
        for (int r = 0; r < 16; ++r) {
            const int row = (r & 3) + 8 * (r >> 2) + 4 * half;  // 32x32 C/D row map
            cand_v[wv][row] = bestv[r];
            cand_i[wv][row] = besti[r];
        }
    }
    __syncthreads();

    // ---- merge: wave 0, one lane per row ----
    if (wv == 0 && lane < 32) {
        const int row = lane;
        float v = cand_v[0][row];
        int i = cand_i[0][row];
#pragma unroll
        for (int w = 1; w < 4; ++w) {
            const float vw = cand_v[w][row];
            const int iw = cand_i[w][row];
            if (vw < v || (vw == v && iw < i)) {
                v = vw;
                i = iw;
            }
        }
        float zn = 0.f;
#pragma unroll
        for (int w = 0; w < 4; ++w) zn += znp[w][row] + znp[w][row + 32];
        out_code[rowBase + row] = (float)i;
        float loss = v + zn;  // ||c-z||^2 for this row
#pragma unroll
        for (int off = 1; off < 32; off <<= 1) loss += __shfl_xor(loss, off, 32);
        if (lane == 0) {
            const int b = blockIdx.x >> 7;  // 128 blocks per batch (4096/32)
            const float val = loss * (1.0f / (4096.0f * 256.0f));
            atomicAdd(&out_loss[b], val);
            atomicAdd(&out_loss[16 + b], val);
        }
    }
}

// ---------------- K4: z_q[row] = P[code[row]]  (pure gather-copy) -----------
__global__ __launch_bounds__(256) void gather_kernel(const float* __restrict__ P,
                                                     const float* __restrict__ code_f,
                                                     float* __restrict__ zq) {
    const int lane = threadIdx.x & 63;
    const int row = blockIdx.x * 4 + (threadIdx.x >> 6);
    const int c = (int)code_f[row];
    const float4* src = (const float4*)(P + (size_t)c * DIN);
    float4* dst = (float4*)(zq + (size_t)row * DIN);
    dst[lane] = src[lane];
    dst[lane + 64] = src[lane + 64];
}

extern "C" void kernel_launch(void* const* d_in, const int* in_sizes, int n_in,
                              void* d_out, int out_size, void* d_ws, size_t ws_size,
                              hipStream_t stream) {
    const float* z_e = (const float*)d_in[0];      // [16,4096,512]
    const float* cbook = (const float*)d_in[1];    // [1024,256]
    const float* W_down = (const float*)d_in[2];   // [256,512]
    const float* W_up = (const float*)d_in[3];     // [512,256]

    float* out = (float*)d_out;
    float* out_zq = out;                           // 33554432
    float* out_zed = out + 33554432;               // 16777216
    float* out_code = out_zed + 16777216;          // 65536
    float* out_loss = out_code + 65536;            // 32

    // ws: [0,4K) cnorm | [4K, 4K+1.5M) swizzles | P (2 MB) overlays swizzles
    // after dist (peak 2101248 B — identical to previous footprint).
    char* wsb = (char*)d_ws;
    float* cnorm = (float*)wsb;
    unsigned short* cb_hi = (unsigned short*)(wsb + 4096);
    unsigned short* cb_lo = (unsigned short*)(wsb + 4096 + 524288);
    unsigned short* wd_hi = (unsigned short*)(wsb + 4096 + 2 * 524288);
    unsigned short* wd_lo = (unsigned short*)(wsb + 4096 + 2 * 524288 + 262144);
    float* P = (float*)(wsb + 4096);               // [1024][512]

    cnorm_kernel<<<KCODES, 256, 0, stream>>>(cbook, cnorm, out_loss);
    swz32_kernel<<<1024, 256, 0, stream>>>(cbook, cb_hi, cb_lo, 256, 262144);
    swz_kernel<<<512, 256, 0, stream>>>(W_down, wd_hi, wd_lo, 512, 131072);

    gemm_down_mfma<<<BT_TOTAL / 64, 256, 0, stream>>>(z_e, wd_hi, wd_lo, out_zed);
    dist_mfma<<<BT_TOTAL / 32, 256, 0, stream>>>(out_zed, cb_hi, cb_lo, cnorm,
                                                 out_code, out_loss);
    // P = cbook @ W_up^T (fp32 VALU; overwrites swizzle area, now dead)
    gemm_rowdot<256, 512><<<dim3(16, 8), 256, 0, stream>>>(cbook, W_up, P);
    gather_kernel<<<BT_TOTAL / 4, 256, 0, stream>>>(P, out_code, out_zq);
}

// Round 3
// 536.649 us; speedup vs baseline: 1.2001x; 1.2001x over previous
//
#include <hip/hip_runtime.h>
#include <math.h>

#define BT_TOTAL 65536
#define DIN 512
#define DEMB 256
#define KCODES 1024

typedef __attribute__((ext_vector_type(8))) short short8;
typedef __attribute__((ext_vector_type(4))) float floatx4;
typedef __attribute__((ext_vector_type(16))) float floatx16;

__device__ __forceinline__ unsigned short f2bf(float x) {
    unsigned u = __float_as_uint(x);
    unsigned r = u + 0x7fffu + ((u >> 16) & 1u);
    return (unsigned short)(r >> 16);
}
__device__ __forceinline__ float bf2f(unsigned short h) {
    return __uint_as_float(((unsigned)h) << 16);
}

// ---------------- K0a: codebook row norms + zero loss outputs ---------------
__global__ __launch_bounds__(256) void cnorm_kernel(const float* __restrict__ cbook,
                                                    float* __restrict__ cnorm,
                                                    float* __restrict__ out_loss) {
    const int k = blockIdx.x;
    const int tid = threadIdx.x;
    float v = cbook[k * DEMB + tid];
    v *= v;
#pragma unroll
    for (int o = 32; o > 0; o >>= 1) v += __shfl_down(v, o);
    __shared__ float ps[4];
    if ((tid & 63) == 0) ps[tid >> 6] = v;
    __syncthreads();
    if (tid == 0) cnorm[k] = ps[0] + ps[1] + ps[2] + ps[3];
    if (k == 0 && tid < 32) out_loss[tid] = 0.0f;
}

// ---------------- K0c: split+swizzle [N][K] row-major into 32x32x16 MFMA
// B-frag order: for col c, depth k:
//   t = c>>5 (32-col tile), s = k>>4 (16-deep chunk),
//   lane = ((k>>3)&1)*32 + (c&31), j = k&7
//   offset = ((t*(K/16) + s)*64 + lane)*8 + j
__global__ __launch_bounds__(256) void swz32_kernel(const float* __restrict__ Bt,
                                                    unsigned short* __restrict__ hi,
                                                    unsigned short* __restrict__ lo,
                                                    int K, int total) {
    const int o = blockIdx.x * 256 + threadIdx.x;
    if (o >= total) return;
    const int j = o & 7;
    const int l = (o >> 3) & 63;
    const int r = o >> 9;
    const int kst = K >> 4;
    const int s = r % kst;
    const int t = r / kst;
    const int c = t * 32 + (l & 31);
    const int k = s * 16 + (l >> 5) * 8 + j;
    const float v = Bt[(size_t)c * K + k];
    const unsigned short h = f2bf(v);
    hi[o] = (unsigned short)h;
    lo[o] = f2bf(v - bf2f(h));
}

// ---------------- fp32 VALU GEMM (for tiny P-matrix): C = A * Bt^T ----------
template <int KD, int NSTR>
__global__ __launch_bounds__(256) void gemm_rowdot(const float* __restrict__ A,
                                                   const float* __restrict__ Bt,
                                                   float* __restrict__ C) {
    __shared__ __align__(16) float As[64][36];
    __shared__ __align__(16) float Bs[64][36];
    const int tid = threadIdx.x;
    const int tx = tid & 15, ty = tid >> 4;
    const int rowBase = blockIdx.x * 64;
    const int colBase = blockIdx.y * 64;
    const int lr = tid >> 2;
    const int lk = (tid & 3) * 8;
    float acc[4][4] = {};
    for (int k0 = 0; k0 < KD; k0 += 32) {
        const float4 a0 = *(const float4*)(A + (size_t)(rowBase + lr) * KD + k0 + lk);
        const float4 a1 = *(const float4*)(A + (size_t)(rowBase + lr) * KD + k0 + lk + 4);
        const float4 b0 = *(const float4*)(Bt + (size_t)(colBase + lr) * KD + k0 + lk);
        const float4 b1 = *(const float4*)(Bt + (size_t)(colBase + lr) * KD + k0 + lk + 4);
        __syncthreads();
        *(float4*)&As[lr][lk] = a0;
        *(float4*)&As[lr][lk + 4] = a1;
        *(float4*)&Bs[lr][lk] = b0;
        *(float4*)&Bs[lr][lk + 4] = b1;
        __syncthreads();
#pragma unroll
        for (int e = 0; e < 32; e += 4) {
            float4 va[4], vb[4];
#pragma unroll
            for (int i = 0; i < 4; ++i) va[i] = *(const float4*)&As[4 * ty + i][e];
#pragma unroll
            for (int j = 0; j < 4; ++j) vb[j] = *(const float4*)&Bs[4 * tx + j][e];
#pragma unroll
            for (int i = 0; i < 4; ++i)
#pragma unroll
                for (int j = 0; j < 4; ++j) {
                    acc[i][j] = fmaf(va[i].x, vb[j].x, acc[i][j]);
                    acc[i][j] = fmaf(va[i].y, vb[j].y, acc[i][j]);
                    acc[i][j] = fmaf(va[i].z, vb[j].z, acc[i][j]);
                    acc[i][j] = fmaf(va[i].w, vb[j].w, acc[i][j]);
                }
        }
    }
#pragma unroll
    for (int i = 0; i < 4; ++i) {
        float4 o = make_float4(acc[i][0], acc[i][1], acc[i][2], acc[i][3]);
        *(float4*)(C + (size_t)(rowBase + 4 * ty + i) * NSTR + colBase + 4 * tx) = o;
    }
}

// ---------------- K1: z_e_down = z_e @ W_down^T ----------------------------
// v2: 32x32x16 MFMA, 2 waves x 32 rows, 8 N-tiles of 32, K=512 in 32 chunks
// of 16. B (swz32 W_down) LDS double-buffered, 1 barrier/phase, T14 split.
__global__ __launch_bounds__(128, 2) void gemm_down_mfma(const float* __restrict__ A,
                                                         const unsigned short* __restrict__ bhi,
                                                         const unsigned short* __restrict__ blo,
                                                         float* __restrict__ C) {
    __shared__ __align__(16) short lds_h[2][8][512];  // [buf][ntile][lane*8]
    __shared__ __align__(16) short lds_l[2][8][512];
    const int tid = threadIdx.x;
    const int lane = tid & 63, wv = tid >> 6;
    const int cc = lane & 31, half = lane >> 5;
    const int rowBase = blockIdx.x * 64 + wv * 32;

    floatx16 acc[8];
#pragma unroll
    for (int t = 0; t < 8; ++t)
#pragma unroll
        for (int r = 0; r < 16; ++r) acc[t][r] = 0.f;

    const float* arow = A + (size_t)(rowBase + cc) * DIN + half * 8;

    // load + convert A chunk 0
    short8 ach, acl;
    {
        const float4 a0 = *(const float4*)(arow);
        const float4 a1 = *(const float4*)(arow + 4);
        const float xs[8] = {a0.x, a0.y, a0.z, a0.w, a1.x, a1.y, a1.z, a1.w};
#pragma unroll
        for (int j = 0; j < 8; ++j) {
            const unsigned short h = f2bf(xs[j]);
            ach[j] = (short)h;
            acl[j] = (short)f2bf(xs[j] - bf2f(h));
        }
    }
    // stage B chunk 0 (all 8 N-tiles, hi+lo = 16 copies over 2 waves)
#pragma unroll
    for (int i = 0; i < 8; ++i) {
        const int c = wv * 8 + i;
        const int t = c >> 1;
        const unsigned short* src = (c & 1) ? blo : bhi;
        const short8 vst = *(const short8*)(src + ((size_t)(t * 32) * 64 + lane) * 8);
        short* dst = (c & 1) ? &lds_l[0][t][lane * 8] : &lds_h[0][t][lane * 8];
        *(short8*)dst = vst;
    }
    __syncthreads();

    int buf = 0;
    for (int s = 0; s < 32; ++s) {
        short8 pf[8];
        float4 av0, av1;
        if (s < 31) {  // T14 issue-early: next-phase B + A loads
#pragma unroll
            for (int i = 0; i < 8; ++i) {
                const int c = wv * 8 + i;
                const int t = c >> 1;
                const unsigned short* src = (c & 1) ? blo : bhi;
                pf[i] = *(const short8*)(src + ((size_t)(t * 32 + s + 1) * 64 + lane) * 8);
            }
            av0 = *(const float4*)(arow + (s + 1) * 16);
            av1 = *(const float4*)(arow + (s + 1) * 16 + 4);
        }
        __builtin_amdgcn_s_setprio(1);
#pragma unroll
        for (int t = 0; t < 8; ++t) {
            const short8 bh = *(const short8*)&lds_h[buf][t][lane * 8];
            const short8 bl = *(const short8*)&lds_l[buf][t][lane * 8];
            acc[t] = __builtin_amdgcn_mfma_f32_32x32x16_bf16(ach, bh, acc[t], 0, 0, 0);
            acc[t] = __builtin_amdgcn_mfma_f32_32x32x16_bf16(acl, bh, acc[t], 0, 0, 0);
            acc[t] = __builtin_amdgcn_mfma_f32_32x32x16_bf16(ach, bl, acc[t], 0, 0, 0);
        }
        __builtin_amdgcn_s_setprio(0);
        if (s < 31) {  // convert next A, write-late B
            const float xs[8] = {av0.x, av0.y, av0.z, av0.w, av1.x, av1.y, av1.z, av1.w};
#pragma unroll
            for (int j = 0; j < 8; ++j) {
                const unsigned short h = f2bf(xs[j]);
                ach[j] = (short)h;
                acl[j] = (short)f2bf(xs[j] - bf2f(h));
            }
#pragma unroll
            for (int i = 0; i < 8; ++i) {
                const int c = wv * 8 + i;
                const int t = c >> 1;
                short* dst = (c & 1) ? &lds_l[buf ^ 1][t][lane * 8]
                                     : &lds_h[buf ^ 1][t][lane * 8];
                *(short8*)dst = pf[i];
            }
        }
        __syncthreads();
        buf ^= 1;
    }
    // epilogue: C[row][col], col = t*32+cc, row via 32x32 C/D map
#pragma unroll
    for (int t = 0; t < 8; ++t)
#pragma unroll
        for (int r = 0; r < 16; ++r) {
            const int row = (r & 3) + 8 * (r >> 2) + 4 * half;
            C[(size_t)(rowBase + row) * DEMB + t * 32 + cc] = acc[t][r];
        }
}

// ---------------- K2: dist + argmin + losses -------------------------------
// v4: round-1 structure (LDS-staged B, T14, 1 barrier/phase) with 2-wave
// blocks: 64 rows/block, grid 1024 -> 4 independent barrier domains per CU.
// Each wave owns 32 rows and processes ALL 1024 codes -> private argmin,
// no cross-wave merge.
#define DIST_CHUNKS(BASE)                                                                     \
    {                                                                                         \
        _Pragma("unroll") for (int s8 = 0; s8 < 8; s8 += 2) {                                 \
            const short8 bh0 = *(const short8*)&lds_h[buf][s8][lane * 8];                     \
            const short8 bl0 = *(const short8*)&lds_l[buf][s8][lane * 8];                     \
            const short8 bh1 = *(const short8*)&lds_h[buf][s8 + 1][lane * 8];                 \
            const short8 bl1 = *(const short8*)&lds_l[buf][s8 + 1][lane * 8];                 \
            accA = __builtin_amdgcn_mfma_f32_32x32x16_bf16(ahi[BASE + s8], bh0, accA, 0, 0, 0);     \
            accB = __builtin_amdgcn_mfma_f32_32x32x16_bf16(ahi[BASE + s8 + 1], bh1, accB, 0, 0, 0); \
            accA = __builtin_amdgcn_mfma_f32_32x32x16_bf16(alo[BASE + s8], bh0, accA, 0, 0, 0);     \
            accB = __builtin_amdgcn_mfma_f32_32x32x16_bf16(alo[BASE + s8 + 1], bh1, accB, 0, 0, 0); \
            accA = __builtin_amdgcn_mfma_f32_32x32x16_bf16(ahi[BASE + s8], bl0, accA, 0, 0, 0);     \
            accB = __builtin_amdgcn_mfma_f32_32x32x16_bf16(ahi[BASE + s8 + 1], bl1, accB, 0, 0, 0); \
        }                                                                                     \
    }

__global__ __launch_bounds__(128, 2) void dist_mfma(const float* __restrict__ zed,
                                                    const unsigned short* __restrict__ chi,
                                                    const unsigned short* __restrict__ clo,
                                                    const float* __restrict__ cnorm,
                                                    float* __restrict__ out_code,
                                                    float* __restrict__ out_loss) {
    __shared__ __align__(16) short lds_h[2][8][512];  // [buf][chunk][lane*8]
    __shared__ __align__(16) short lds_l[2][8][512];
    __shared__ float cn_s[KCODES];
    __shared__ float znorm_s[2][32];
    const int tid = threadIdx.x;
    const int lane = tid & 63, wv = tid >> 6;
    const int cc = lane & 31, half = lane >> 5;
    const int rowBase = blockIdx.x * 64 + wv * 32;

    *(float4*)&cn_s[tid * 8] = *(const float4*)(cnorm + tid * 8);
    *(float4*)&cn_s[tid * 8 + 4] = *(const float4*)(cnorm + tid * 8 + 4);

    // A fragments (hi/lo) for this wave's 32 rows, all K=256; plus row norms.
    short8 ahi[16], alo[16];
    float zn = 0.f;
    const float* arow = zed + (size_t)(rowBase + cc) * DEMB + half * 8;
#pragma unroll
    for (int s = 0; s < 16; ++s) {
        const float4 v0 = *(const float4*)(arow + s * 16);
        const float4 v1 = *(const float4*)(arow + s * 16 + 4);
        const float xs[8] = {v0.x, v0.y, v0.z, v0.w, v1.x, v1.y, v1.z, v1.w};
#pragma unroll
        for (int j = 0; j < 8; ++j) {
            const unsigned short h = f2bf(xs[j]);
            ahi[s][j] = (short)h;
            alo[s][j] = (short)f2bf(xs[j] - bf2f(h));
            zn = fmaf(xs[j], xs[j], zn);
        }
    }
    zn += __shfl_xor(zn, 32, 64);  // combine the two k-halves of row cc
    if (half == 0) znorm_s[wv][cc] = zn;

    // stage phase 0 (tile 0, chunks 0..7): 16 copies over 2 waves
#pragma unroll
    for (int i = 0; i < 8; ++i) {
        const int c = wv * 8 + i;
        const int s8 = c >> 1;
        const unsigned short* src = (c & 1) ? clo : chi;
        const short8 vst = *(const short8*)(src + ((size_t)s8 * 64 + lane) * 8);
        short* dst = (c & 1) ? &lds_l[0][s8][lane * 8] : &lds_h[0][s8][lane * 8];
        *(short8*)dst = vst;
    }
    __syncthreads();

    floatx16 accA, accB;
    float bestv[16];
    int besti[16];
#pragma unroll
    for (int r = 0; r < 16; ++r) {
        accA[r] = 0.f;
        accB[r] = 0.f;
        bestv[r] = INFINITY;
        besti[r] = 0;
    }
    int buf = 0;

    for (int ph = 0; ph < 64; ++ph) {
        const int t = ph >> 1;
        // T14 issue-early: load next phase's fragments into regs
        short8 pf[8];
        if (ph < 63) {
            const int tn = (ph + 1) >> 1;
            const int sb = ((ph + 1) & 1) * 8;
#pragma unroll
            for (int i = 0; i < 8; ++i) {
                const int c = wv * 8 + i;
                const int s8 = c >> 1;
                const unsigned short* src = (c & 1) ? clo : chi;
                pf[i] = *(const short8*)(src + ((size_t)(tn * 16 + sb + s8) * 64 + lane) * 8);
            }
        }
        __builtin_amdgcn_s_setprio(1);
        if ((ph & 1) == 0) {
            DIST_CHUNKS(0)
        } else {
            DIST_CHUNKS(8)
        }
        __builtin_amdgcn_s_setprio(0);
        if (ph & 1) {  // K complete for tile t: finalize 32x32 distances
            const float cn = cn_s[t * 32 + cc];
            const int code = t * 32 + cc;
#pragma unroll
            for (int r = 0; r < 16; ++r) {
                const float d = fmaf(-2.f, accA[r] + accB[r], cn);
                if (d < bestv[r]) {
                    bestv[r] = d;
                    besti[r] = code;
                }
                accA[r] = 0.f;
                accB[r] = 0.f;
            }
        }
        // T14 write-late: LDS write for next phase
        if (ph < 63) {
#pragma unroll
            for (int i = 0; i < 8; ++i) {
                const int c = wv * 8 + i;
                const int s8 = c >> 1;
                short* dst = (c & 1) ? &lds_l[buf ^ 1][s8][lane * 8]
                                     : &lds_h[buf ^ 1][s8][lane * 8];
                *(short8*)dst = pf[i];
            }
        }
        __syncthreads();
        buf ^= 1;
    }

    // per-wave reduce across the 32 code-lanes (first-index tie-break)
#pragma unroll
    for (int off = 1; off < 32; off <<= 1) {
#pragma unroll
        for (int r = 0; r < 16; ++r) {
            const float ov = __shfl_xor(bestv[r], off, 64);
            const int oi = __shfl_xor(besti[r], off, 64);
            if (ov < bestv[r] || (ov == bestv[r] && oi < besti[r])) {
                bestv[r] = ov;
                besti[r] = oi;
            }
        }
    }
    float ls = 0.f;
    if (cc == 0) {  // lanes 0 and 32 hold the wave's 32 rows between them
#pragma unroll
        for (int r = 0; r < 16; ++r) {
            const int row = (r & 3) + 8 * (r >> 2) + 4 * half;  // 32x32 C/D row map
            out_code[rowBase + row] = (float)besti[r];
            ls += bestv[r] + znorm_s[wv][row];  // ||c-z||^2
        }
    }
    ls += __shfl_xor(ls, 32, 64);
    if (lane == 0) {
        const int b = blockIdx.x >> 6;  // 64 blocks per batch (4096/64)
        const float val = ls * (1.0f / (4096.0f * 256.0f));
        atomicAdd(&out_loss[b], val);
        atomicAdd(&out_loss[16 + b], val);
    }
}

// ---------------- K4: z_q[row] = P[code[row]]  (pure gather-copy) -----------
__global__ __launch_bounds__(256) void gather_kernel(const float* __restrict__ P,
                                                     const float* __restrict__ code_f,
                                                     float* __restrict__ zq) {
    const int lane = threadIdx.x & 63;
    const int row = blockIdx.x * 4 + (threadIdx.x >> 6);
    const int c = (int)code_f[row];
    const float4* src = (const float4*)(P + (size_t)c * DIN);
    float4* dst = (float4*)(zq + (size_t)row * DIN);
    dst[lane] = src[lane];
    dst[lane + 64] = src[lane + 64];
}

extern "C" void kernel_launch(void* const* d_in, const int* in_sizes, int n_in,
                              void* d_out, int out_size, void* d_ws, size_t ws_size,
                              hipStream_t stream) {
    const float* z_e = (const float*)d_in[0];      // [16,4096,512]
    const float* cbook = (const float*)d_in[1];    // [1024,256]
    const float* W_down = (const float*)d_in[2];   // [256,512]
    const float* W_up = (const float*)d_in[3];     // [512,256]

    float* out = (float*)d_out;
    float* out_zq = out;                           // 33554432
    float* out_zed = out + 33554432;               // 16777216
    float* out_code = out_zed + 16777216;          // 65536
    float* out_loss = out_code + 65536;            // 32

    // ws: [0,4K) cnorm | [4K, 4K+1.5M) swizzles | P (2 MB) overlays swizzles
    // after dist (peak 2101248 B).
    char* wsb = (char*)d_ws;
    float* cnorm = (float*)wsb;
    unsigned short* cb_hi = (unsigned short*)(wsb + 4096);
    unsigned short* cb_lo = (unsigned short*)(wsb + 4096 + 524288);
    unsigned short* wd_hi = (unsigned short*)(wsb + 4096 + 2 * 524288);
    unsigned short* wd_lo = (unsigned short*)(wsb + 4096 + 2 * 524288 + 262144);
    float* P = (float*)(wsb + 4096);               // [1024][512]

    cnorm_kernel<<<KCODES, 256, 0, stream>>>(cbook, cnorm, out_loss);
    swz32_kernel<<<1024, 256, 0, stream>>>(cbook, cb_hi, cb_lo, 256, 262144);
    swz32_kernel<<<512, 256, 0, stream>>>(W_down, wd_hi, wd_lo, 512, 131072);

    gemm_down_mfma<<<BT_TOTAL / 64, 128, 0, stream>>>(z_e, wd_hi, wd_lo, out_zed);
    dist_mfma<<<BT_TOTAL / 64, 128, 0, stream>>>(out_zed, cb_hi, cb_lo, cnorm,
                                                 out_code, out_loss);
    // P = cbook @ W_up^T (fp32 VALU; overwrites swizzle area, now dead)
    gemm_rowdot<256, 512><<<dim3(16, 8), 256, 0, stream>>>(cbook, W_up, P);
    gather_kernel<<<BT_TOTAL / 4, 256, 0, stream>>>(P, out_code, out_zq);
}

// Round 5
// 458.391 us; speedup vs baseline: 1.4050x; 1.1707x over previous
//
#include <hip/hip_runtime.h>
#include <math.h>

#define BT_TOTAL 65536
#define DIN 512
#define DEMB 256
#define KCODES 1024

typedef __attribute__((ext_vector_type(8))) short short8;
typedef __attribute__((ext_vector_type(4))) float floatx4;
typedef __attribute__((ext_vector_type(16))) float floatx16;

__device__ __forceinline__ unsigned short f2bf(float x) {
    unsigned u = __float_as_uint(x);
    unsigned r = u + 0x7fffu + ((u >> 16) & 1u);
    return (unsigned short)(r >> 16);
}
__device__ __forceinline__ float bf2f(unsigned short h) {
    return __uint_as_float(((unsigned)h) << 16);
}

// ---------------- K0a: codebook row norms + zero loss outputs ---------------
__global__ __launch_bounds__(256) void cnorm_kernel(const float* __restrict__ cbook,
                                                    float* __restrict__ cnorm,
                                                    float* __restrict__ out_loss) {
    const int k = blockIdx.x;
    const int tid = threadIdx.x;
    float v = cbook[k * DEMB + tid];
    v *= v;
#pragma unroll
    for (int o = 32; o > 0; o >>= 1) v += __shfl_down(v, o);
    __shared__ float ps[4];
    if ((tid & 63) == 0) ps[tid >> 6] = v;
    __syncthreads();
    if (tid == 0) cnorm[k] = ps[0] + ps[1] + ps[2] + ps[3];
    if (k == 0 && tid < 32) out_loss[tid] = 0.0f;
}

// ---------------- K0c: split+swizzle [N][K] row-major into 32x32x16 MFMA
// B-frag order: for col c, depth k:
//   t = c>>5 (32-col tile), s = k>>4 (16-deep chunk),
//   lane = ((k>>3)&1)*32 + (c&31), j = k&7
//   offset = ((t*(K/16) + s)*64 + lane)*8 + j
__global__ __launch_bounds__(256) void swz32_kernel(const float* __restrict__ Bt,
                                                    unsigned short* __restrict__ hi,
                                                    unsigned short* __restrict__ lo,
                                                    int K, int total) {
    const int o = blockIdx.x * 256 + threadIdx.x;
    if (o >= total) return;
    const int j = o & 7;
    const int l = (o >> 3) & 63;
    const int r = o >> 9;
    const int kst = K >> 4;
    const int s = r % kst;
    const int t = r / kst;
    const int c = t * 32 + (l & 31);
    const int k = s * 16 + (l >> 5) * 8 + j;
    const float v = Bt[(size_t)c * K + k];
    const unsigned short h = f2bf(v);
    hi[o] = (unsigned short)h;
    lo[o] = f2bf(v - bf2f(h));
}

// ---------------- fp32 VALU GEMM (for tiny P-matrix): C = A * Bt^T ----------
template <int KD, int NSTR>
__global__ __launch_bounds__(256) void gemm_rowdot(const float* __restrict__ A,
                                                   const float* __restrict__ Bt,
                                                   float* __restrict__ C) {
    __shared__ __align__(16) float As[64][36];
    __shared__ __align__(16) float Bs[64][36];
    const int tid = threadIdx.x;
    const int tx = tid & 15, ty = tid >> 4;
    const int rowBase = blockIdx.x * 64;
    const int colBase = blockIdx.y * 64;
    const int lr = tid >> 2;
    const int lk = (tid & 3) * 8;
    float acc[4][4] = {};
    for (int k0 = 0; k0 < KD; k0 += 32) {
        const float4 a0 = *(const float4*)(A + (size_t)(rowBase + lr) * KD + k0 + lk);
        const float4 a1 = *(const float4*)(A + (size_t)(rowBase + lr) * KD + k0 + lk + 4);
        const float4 b0 = *(const float4*)(Bt + (size_t)(colBase + lr) * KD + k0 + lk);
        const float4 b1 = *(const float4*)(Bt + (size_t)(colBase + lr) * KD + k0 + lk + 4);
        __syncthreads();
        *(float4*)&As[lr][lk] = a0;
        *(float4*)&As[lr][lk + 4] = a1;
        *(float4*)&Bs[lr][lk] = b0;
        *(float4*)&Bs[lr][lk + 4] = b1;
        __syncthreads();
#pragma unroll
        for (int e = 0; e < 32; e += 4) {
            float4 va[4], vb[4];
#pragma unroll
            for (int i = 0; i < 4; ++i) va[i] = *(const float4*)&As[4 * ty + i][e];
#pragma unroll
            for (int j = 0; j < 4; ++j) vb[j] = *(const float4*)&Bs[4 * tx + j][e];
#pragma unroll
            for (int i = 0; i < 4; ++i)
#pragma unroll
                for (int j = 0; j < 4; ++j) {
                    acc[i][j] = fmaf(va[i].x, vb[j].x, acc[i][j]);
                    acc[i][j] = fmaf(va[i].y, vb[j].y, acc[i][j]);
                    acc[i][j] = fmaf(va[i].z, vb[j].z, acc[i][j]);
                    acc[i][j] = fmaf(va[i].w, vb[j].w, acc[i][j]);
                }
        }
    }
#pragma unroll
    for (int i = 0; i < 4; ++i) {
        float4 o = make_float4(acc[i][0], acc[i][1], acc[i][2], acc[i][3]);
        *(float4*)(C + (size_t)(rowBase + 4 * ty + i) * NSTR + colBase + 4 * tx) = o;
    }
}

// ---------------- K1: z_e_down = z_e @ W_down^T ----------------------------
// v3: 32x32x16 MFMA, 4 waves x 32 rows (128 rows/block), phase = 2 k-chunks
// (32-deep), 16 phases over K=512. B LDS double-buffered (64 KB), T14 split,
// 8 independent acc chains.
__global__ __launch_bounds__(256, 2) void gemm_down_mfma(const float* __restrict__ A,
                                                         const unsigned short* __restrict__ bhi,
                                                         const unsigned short* __restrict__ blo,
                                                         float* __restrict__ C) {
    __shared__ __align__(16) short lds_h[2][2][8][512];  // [buf][kc][tile][lane*8]
    __shared__ __align__(16) short lds_l[2][2][8][512];
    const int tid = threadIdx.x;
    const int lane = tid & 63, wv = tid >> 6;
    const int cc = lane & 31, half = lane >> 5;
    const int rowBase = blockIdx.x * 128 + wv * 32;

    floatx16 acc[8];
#pragma unroll
    for (int t = 0; t < 8; ++t)
#pragma unroll
        for (int r = 0; r < 16; ++r) acc[t][r] = 0.f;

    const float* arow = A + (size_t)(rowBase + cc) * DIN + half * 8;

    // A pair 0: chunks 0,1 -> ach/acl[2]
    short8 ach[2], acl[2];
    {
        const float4 a00 = *(const float4*)(arow);
        const float4 a01 = *(const float4*)(arow + 4);
        const float4 a10 = *(const float4*)(arow + 16);
        const float4 a11 = *(const float4*)(arow + 20);
        const float xs[16] = {a00.x, a00.y, a00.z, a00.w, a01.x, a01.y, a01.z, a01.w,
                              a10.x, a10.y, a10.z, a10.w, a11.x, a11.y, a11.z, a11.w};
#pragma unroll
        for (int kc = 0; kc < 2; ++kc)
#pragma unroll
            for (int j = 0; j < 8; ++j) {
                const float x = xs[kc * 8 + j];
                const unsigned short h = f2bf(x);
                ach[kc][j] = (short)h;
                acl[kc][j] = (short)f2bf(x - bf2f(h));
            }
    }
    // stage B pair 0 -> buf0: 32 copies of 1 KB over 4 waves (8 each)
#pragma unroll
    for (int i = 0; i < 8; ++i) {
        const int c = wv * 8 + i;
        const int t = c >> 2;
        const int kc = (c >> 1) & 1;
        const unsigned short* src = (c & 1) ? blo : bhi;
        const short8 vst = *(const short8*)(src + ((size_t)(t * 32 + kc) * 64 + lane) * 8);
        short* dst = (c & 1) ? &lds_l[0][kc][t][lane * 8] : &lds_h[0][kc][t][lane * 8];
        *(short8*)dst = vst;
    }
    __syncthreads();

    int buf = 0;
    for (int p = 0; p < 16; ++p) {
        short8 pf[8];
        float4 av[4];
        if (p < 15) {  // T14 issue-early: B + A for pair p+1
#pragma unroll
            for (int i = 0; i < 8; ++i) {
                const int c = wv * 8 + i;
                const int t = c >> 2;
                const int kc = (c >> 1) & 1;
                const unsigned short* src = (c & 1) ? blo : bhi;
                pf[i] = *(const short8*)(src +
                                         ((size_t)(t * 32 + (p + 1) * 2 + kc) * 64 + lane) * 8);
            }
            av[0] = *(const float4*)(arow + (p + 1) * 32);
            av[1] = *(const float4*)(arow + (p + 1) * 32 + 4);
            av[2] = *(const float4*)(arow + (p + 1) * 32 + 16);
            av[3] = *(const float4*)(arow + (p + 1) * 32 + 20);
        }
        __builtin_amdgcn_s_setprio(1);
#pragma unroll
        for (int kc = 0; kc < 2; ++kc)
#pragma unroll
            for (int t = 0; t < 8; ++t) {
                const short8 bh = *(const short8*)&lds_h[buf][kc][t][lane * 8];
                const short8 bl = *(const short8*)&lds_l[buf][kc][t][lane * 8];
                acc[t] = __builtin_amdgcn_mfma_f32_32x32x16_bf16(ach[kc], bh, acc[t], 0, 0, 0);
                acc[t] = __builtin_amdgcn_mfma_f32_32x32x16_bf16(acl[kc], bh, acc[t], 0, 0, 0);
                acc[t] = __builtin_amdgcn_mfma_f32_32x32x16_bf16(ach[kc], bl, acc[t], 0, 0, 0);
            }
        __builtin_amdgcn_s_setprio(0);
        if (p < 15) {  // convert next A, write-late B
            const float xs[16] = {av[0].x, av[0].y, av[0].z, av[0].w,
                                  av[1].x, av[1].y, av[1].z, av[1].w,
                                  av[2].x, av[2].y, av[2].z, av[2].w,
                                  av[3].x, av[3].y, av[3].z, av[3].w};
#pragma unroll
            for (int kc = 0; kc < 2; ++kc)
#pragma unroll
                for (int j = 0; j < 8; ++j) {
                    const float x = xs[kc * 8 + j];
                    const unsigned short h = f2bf(x);
                    ach[kc][j] = (short)h;
                    acl[kc][j] = (short)f2bf(x - bf2f(h));
                }
#pragma unroll
            for (int i = 0; i < 8; ++i) {
                const int c = wv * 8 + i;
                const int t = c >> 2;
                const int kc = (c >> 1) & 1;
                short* dst = (c & 1) ? &lds_l[buf ^ 1][kc][t][lane * 8]
                                     : &lds_h[buf ^ 1][kc][t][lane * 8];
                *(short8*)dst = pf[i];
            }
        }
        __syncthreads();
        buf ^= 1;
    }
    // epilogue: C[row][col], col = t*32+cc, row via 32x32 C/D map
#pragma unroll
    for (int t = 0; t < 8; ++t)
#pragma unroll
        for (int r = 0; r < 16; ++r) {
            const int row = (r & 3) + 8 * (r >> 2) + 4 * half;
            C[(size_t)(rowBase + row) * DEMB + t * 32 + cc] = acc[t][r];
        }
}

// ---------------- K2: dist + argmin + losses -------------------------------
// v5: round-1 4-wave structure with FAT phases: one full code-tile (K=256,
// 16 chunks) per phase -> 32 phases, 48 MFMA + 32 ds_read + 8 stage-copies
// per wave per phase, ONE barrier per phase. LDS dbuf 64 KB + cn 4 KB ->
// 2 blocks/CU, 8 waves/CU.
__global__ __launch_bounds__(256, 2) void dist_mfma(const float* __restrict__ zed,
                                                    const unsigned short* __restrict__ chi,
                                                    const unsigned short* __restrict__ clo,
                                                    const float* __restrict__ cnorm,
                                                    float* __restrict__ out_code,
                                                    float* __restrict__ out_loss) {
    __shared__ __align__(16) short lds_h[2][16][512];  // [buf][chunk][lane*8]
    __shared__ __align__(16) short lds_l[2][16][512];
    __shared__ float cn_s[KCODES];
    __shared__ float znorm_s[4][32];
    __shared__ float blockSum;
    const int tid = threadIdx.x;
    const int lane = tid & 63, wv = tid >> 6;
    const int cc = lane & 31, half = lane >> 5;
    const int rowBase = blockIdx.x * 128 + wv * 32;

    *(float4*)&cn_s[tid * 4] = *(const float4*)(cnorm + tid * 4);
    if (tid == 0) blockSum = 0.f;

    // A fragments (hi/lo) for this wave's 32 rows, all K=256; plus row norms.
    short8 ahi[16], alo[16];
    float zn = 0.f;
    const float* arow = zed + (size_t)(rowBase + cc) * DEMB + half * 8;
#pragma unroll
    for (int s = 0; s < 16; ++s) {
        const float4 v0 = *(const float4*)(arow + s * 16);
        const float4 v1 = *(const float4*)(arow + s * 16 + 4);
        const float xs[8] = {v0.x, v0.y, v0.z, v0.w, v1.x, v1.y, v1.z, v1.w};
#pragma unroll
        for (int j = 0; j < 8; ++j) {
            const unsigned short h = f2bf(xs[j]);
            ahi[s][j] = (short)h;
            alo[s][j] = (short)f2bf(xs[j] - bf2f(h));
            zn = fmaf(xs[j], xs[j], zn);
        }
    }
    zn += __shfl_xor(zn, 32, 64);  // combine the two k-halves of row cc
    if (half == 0) znorm_s[wv][cc] = zn;

    // stage tile 0 -> buf 0: 32 copies of 1 KB over 4 waves (8 each)
#pragma unroll
    for (int i = 0; i < 8; ++i) {
        const int c = wv * 8 + i;
        const int s8 = c >> 1;
        const unsigned short* src = (c & 1) ? clo : chi;
        const short8 vst = *(const short8*)(src + ((size_t)s8 * 64 + lane) * 8);
        short* dst = (c & 1) ? &lds_l[0][s8][lane * 8] : &lds_h[0][s8][lane * 8];
        *(short8*)dst = vst;
    }
    __syncthreads();

    floatx16 accA, accB;
    float bestv[16];
    int besti[16];
#pragma unroll
    for (int r = 0; r < 16; ++r) {
        accA[r] = 0.f;
        accB[r] = 0.f;
        bestv[r] = INFINITY;
        besti[r] = 0;
    }
    int buf = 0;

    for (int t = 0; t < 32; ++t) {
        // T14 issue-early: load next tile's fragments into regs
        short8 pf[8];
        if (t < 31) {
#pragma unroll
            for (int i = 0; i < 8; ++i) {
                const int c = wv * 8 + i;
                const int s8 = c >> 1;
                const unsigned short* src = (c & 1) ? clo : chi;
                pf[i] = *(const short8*)(src + ((size_t)((t + 1) * 16 + s8) * 64 + lane) * 8);
            }
        }
        __builtin_amdgcn_s_setprio(1);
#pragma unroll
        for (int s8 = 0; s8 < 16; s8 += 2) {
            const short8 bh0 = *(const short8*)&lds_h[buf][s8][lane * 8];
            const short8 bl0 = *(const short8*)&lds_l[buf][s8][lane * 8];
            const short8 bh1 = *(const short8*)&lds_h[buf][s8 + 1][lane * 8];
            const short8 bl1 = *(const short8*)&lds_l[buf][s8 + 1][lane * 8];
            accA = __builtin_amdgcn_mfma_f32_32x32x16_bf16(ahi[s8], bh0, accA, 0, 0, 0);
            accB = __builtin_amdgcn_mfma_f32_32x32x16_bf16(ahi[s8 + 1], bh1, accB, 0, 0, 0);
            accA = __builtin_amdgcn_mfma_f32_32x32x16_bf16(alo[s8], bh0, accA, 0, 0, 0);
            accB = __builtin_amdgcn_mfma_f32_32x32x16_bf16(alo[s8 + 1], bh1, accB, 0, 0, 0);
            accA = __builtin_amdgcn_mfma_f32_32x32x16_bf16(ahi[s8], bl0, accA, 0, 0, 0);
            accB = __builtin_amdgcn_mfma_f32_32x32x16_bf16(ahi[s8 + 1], bl1, accB, 0, 0, 0);
        }
        __builtin_amdgcn_s_setprio(0);
        // finalize tile t: 32x32 distances for codes t*32..t*32+31
        {
            const float cn = cn_s[t * 32 + cc];
            const int code = t * 32 + cc;
#pragma unroll
            for (int r = 0; r < 16; ++r) {
                const float d = fmaf(-2.f, accA[r] + accB[r], cn);
                if (d < bestv[r]) {
                    bestv[r] = d;
                    besti[r] = code;
                }
                accA[r] = 0.f;
                accB[r] = 0.f;
            }
        }
        // T14 write-late: LDS write for next tile
        if (t < 31) {
#pragma unroll
            for (int i = 0; i < 8; ++i) {
                const int c = wv * 8 + i;
                const int s8 = c >> 1;
                short* dst = (c & 1) ? &lds_l[buf ^ 1][s8][lane * 8]
                                     : &lds_h[buf ^ 1][s8][lane * 8];
                *(short8*)dst = pf[i];
            }
        }
        __syncthreads();
        buf ^= 1;
    }

    // per-wave reduce across the 32 code-lanes (first-index tie-break)
#pragma unroll
    for (int off = 1; off < 32; off <<= 1) {
#pragma unroll
        for (int r = 0; r < 16; ++r) {
            const float ov = __shfl_xor(bestv[r], off, 64);
            const int oi = __shfl_xor(besti[r], off, 64);
            if (ov < bestv[r] || (ov == bestv[r] && oi < besti[r])) {
                bestv[r] = ov;
                besti[r] = oi;
            }
        }
    }
    if (cc == 0) {  // lanes 0 and 32 hold the wave's 32 rows between them
        float ls = 0.f;
#pragma unroll
        for (int r = 0; r < 16; ++r) {
            const int row = (r & 3) + 8 * (r >> 2) + 4 * half;  // 32x32 C/D row map
            out_code[rowBase + row] = (float)besti[r];
            ls += bestv[r] + znorm_s[wv][row];  // ||c-z||^2
        }
        atomicAdd(&blockSum, ls);
    }
    __syncthreads();
    if (tid == 0) {
        const int b = blockIdx.x >> 5;  // 32 blocks per batch (4096/128)
        const float v = blockSum * (1.0f / (4096.0f * 256.0f));
        atomicAdd(&out_loss[b], v);
        atomicAdd(&out_loss[16 + b], v);
    }
}

// ---------------- K4: z_q[row] = P[code[row]]  (pure gather-copy) -----------
__global__ __launch_bounds__(256) void gather_kernel(const float* __restrict__ P,
                                                     const float* __restrict__ code_f,
                                                     float* __restrict__ zq) {
    const int lane = threadIdx.x & 63;
    const int row = blockIdx.x * 4 + (threadIdx.x >> 6);
    const int c = (int)code_f[row];
    const float4* src = (const float4*)(P + (size_t)c * DIN);
    float4* dst = (float4*)(zq + (size_t)row * DIN);
    dst[lane] = src[lane];
    dst[lane + 64] = src[lane + 64];
}

extern "C" void kernel_launch(void* const* d_in, const int* in_sizes, int n_in,
                              void* d_out, int out_size, void* d_ws, size_t ws_size,
                              hipStream_t stream) {
    const float* z_e = (const float*)d_in[0];      // [16,4096,512]
    const float* cbook = (const float*)d_in[1];    // [1024,256]
    const float* W_down = (const float*)d_in[2];   // [256,512]
    const float* W_up = (const float*)d_in[3];     // [512,256]

    float* out = (float*)d_out;
    float* out_zq = out;                           // 33554432
    float* out_zed = out + 33554432;               // 16777216
    float* out_code = out_zed + 16777216;          // 65536
    float* out_loss = out_code + 65536;            // 32

    // ws: [0,4K) cnorm | [4K, 4K+1.5M) swizzles | P (2 MB) overlays swizzles
    // after dist (peak 2101248 B).
    char* wsb = (char*)d_ws;
    float* cnorm = (float*)wsb;
    unsigned short* cb_hi = (unsigned short*)(wsb + 4096);
    unsigned short* cb_lo = (unsigned short*)(wsb + 4096 + 524288);
    unsigned short* wd_hi = (unsigned short*)(wsb + 4096 + 2 * 524288);
    unsigned short* wd_lo = (unsigned short*)(wsb + 4096 + 2 * 524288 + 262144);
    float* P = (float*)(wsb + 4096);               // [1024][512]

    cnorm_kernel<<<KCODES, 256, 0, stream>>>(cbook, cnorm, out_loss);
    swz32_kernel<<<1024, 256, 0, stream>>>(cbook, cb_hi, cb_lo, 256, 262144);
    swz32_kernel<<<512, 256, 0, stream>>>(W_down, wd_hi, wd_lo, 512, 131072);

    gemm_down_mfma<<<BT_TOTAL / 128, 256, 0, stream>>>(z_e, wd_hi, wd_lo, out_zed);
    dist_mfma<<<BT_TOTAL / 128, 256, 0, stream>>>(out_zed, cb_hi, cb_lo, cnorm,
                                                  out_code, out_loss);
    // P = cbook @ W_up^T (fp32 VALU; overwrites swizzle area, now dead)
    gemm_rowdot<256, 512><<<dim3(16, 8), 256, 0, stream>>>(cbook, W_up, P);
    gather_kernel<<<BT_TOTAL / 4, 256, 0, stream>>>(P, out_code, out_zq);
}